// Round 16
// baseline (162.117 us; speedup 1.0000x reference)
//
#include <hip/hip_runtime.h>
#include <stdint.h>

#define ASG __attribute__((address_space(1)))
#define ASL __attribute__((address_space(3)))

typedef __bf16 bf16x8 __attribute__((ext_vector_type(8)));
typedef float f32x4 __attribute__((ext_vector_type(4)));

__device__ __forceinline__ unsigned short f2bf(float f) {
  unsigned int u = __builtin_bit_cast(unsigned int, f);
  u = (u + 0x7fffu + ((u >> 16) & 1u)) >> 16;
  return (unsigned short)u;
}

// ---------------- fused prep: converts X,Wq,Wk,Wv to bf16 + bias concat ----------------
__global__ __launch_bounds__(256) void k_prep(
    const float* __restrict__ X, const float* __restrict__ Wq,
    const float* __restrict__ Wk, const float* __restrict__ Wv,
    const float* __restrict__ bq, const float* __restrict__ bk,
    const float* __restrict__ bv,
    unsigned short* __restrict__ Xb, float* __restrict__ biasF) {
  const int bid = blockIdx.x, tid = threadIdx.x;
  unsigned short* Wb = Xb + 8388608;
  if (bid < 11264) {
    const float* src;
    ushort4* dst;
    int j;
    if (bid < 8192) {
      j = bid * 256 + tid; src = X; dst = (ushort4*)Xb;
    } else {
      int w = (bid - 8192) >> 10;
      j = ((bid - 8192) & 1023) * 256 + tid;
      src = (w == 0) ? Wq : (w == 1 ? Wk : Wv);
      dst = (ushort4*)(Wb + (long)w * 1048576);
    }
    float4 v = reinterpret_cast<const float4*>(src)[j];
    ushort4 o;
    o.x = f2bf(v.x); o.y = f2bf(v.y); o.z = f2bf(v.z); o.w = f2bf(v.w);
    dst[j] = o;
  } else {
    int i = (bid - 11264) * 256 + tid;
    if (i < 3072)
      biasF[i] = (i < 1024) ? bq[i] : (i < 2048 ? bk[i - 1024] : bv[i - 2048]);
  }
}

// =====================================================================
// R10-proven gemm3q: 128x256 tile, BK=32, 8 waves (2Mx4N, wave-tile 64x64),
// 3-buffer LDS ring (72KB -> 2 blocks/CU), ONE barrier per K-tile, counted
// lgkmcnt between ds_read and MFMA, next-tile A+B01 prefetched after the
// barrier, vmcnt(3) = ring-distance-2 staging (3 GLs/tile).
// C[m][n] = alpha * sum_k A[m][k]*B[n][k] (+bias[n])
// LDS buf b at b*24576: A [128][32] bf16 (8KB), B [256][32] (16KB), 64B rows.
// Swizzle (64B rows, 4x16B blocks): blk ^= (row>>1)&3 (2-way alias = free).
// Applied on global SOURCE of global_load_lds (linear dest) + ds_read blocks.
// OUT_MODE: 0=bf16, 1=f32, 3=bf16 but V-cols (bn0>=2048) -> VtOut[b][h][s].
// SWZ (R15-proven, -9us on scores+PV): 1D grid, lid&7 = XCD slot,
// bz=(lid&7)>>1 so each XCD-pair's L2 caches one batch's B-panel; bijective.
// =====================================================================
template <int OUT_MODE, int BIAS, int SWZ>
__global__ __launch_bounds__(512, 4) void gemm3q(
    const unsigned short* __restrict__ A, const unsigned short* __restrict__ B,
    void* __restrict__ Cv, const float* __restrict__ bias,
    unsigned short* __restrict__ VtOut, int nx,
    int lda, int ldb, int ldc, int K, float alpha,
    long sA, long sB, long sC) {
  __shared__ __align__(16) char smem[73728];
  const int tid = threadIdx.x;
  const int wid = tid >> 6, lane = tid & 63;
  const int wr = wid >> 2, wc = wid & 3;
  int bx, by, bz;
  if constexpr (SWZ) {
    const int lid = blockIdx.x;
    const int xcd = lid & 7;
    bz = xcd >> 1;
    const int idx = ((lid >> 3) << 1) + (xcd & 1);
    bx = idx % nx;
    by = idx / nx;
  } else {
    bx = blockIdx.x; by = blockIdx.y; bz = blockIdx.z;
  }
  const int bm0 = by << 7, bn0 = bx << 8;
  A += (long)bz * sA;
  B += (long)bz * sB;
  const int NT = K >> 5;  // 32-wide K tiles

  // ---- staging source addresses (per-lane), swizzle pre-applied ----
  const int srow = tid >> 2;                                // 0..127
  const int scol = (((tid & 3) ^ ((srow >> 1) & 3)) << 3);  // elem col in 32
  long gA0, gB[2];
  gA0 = (long)(bm0 + srow) * lda + scol;
#pragma unroll
  for (int u = 0; u < 2; ++u)
    gB[u] = (long)(bn0 + u * 128 + srow) * ldb + scol;

#define STG(PTR, GOFF, KK, LDSOFF)                                             \
  __builtin_amdgcn_global_load_lds((ASG const void*)((PTR) + (GOFF) + ((KK) << 5)), \
      (ASL void*)(smem + (LDSOFF) + wid * 1024), 16, 0, 0)

#define STG_ALL(KK, SB_) do { int kk = (KK); if (kk >= NT) kk -= NT;           \
    STG(A, gA0, kk, (SB_));                                                    \
    STG(B, gB[0], kk, (SB_) + 8192);                                           \
    STG(B, gB[1], kk, (SB_) + 16384); } while (0)

  // ---- ds_read byte offsets (64B rows) ----
  const int L = lane & 15;
  const int blk = ((lane >> 4) ^ ((L >> 1) & 3)) << 4;  // swizzled 16B block
  int aoff[4], boff[4];
#pragma unroll
  for (int mf = 0; mf < 4; ++mf)
    aoff[mf] = ((wr * 64 + mf * 16 + L) << 6) + blk;
#pragma unroll
  for (int nf = 0; nf < 4; ++nf)
    boff[nf] = 8192 + ((wc * 64 + nf * 16 + L) << 6) + blk;

  bf16x8 afr[4];
  bf16x8 b01[2], b23[2];
  f32x4 acc[4][4] = {};

#define RDA(CB) do { _Pragma("unroll") for (int mf = 0; mf < 4; ++mf)          \
      afr[mf] = *(const bf16x8*)(smem + (CB) + aoff[mf]); } while (0)
#define RDB01(CB) do { _Pragma("unroll") for (int nf = 0; nf < 2; ++nf)        \
      b01[nf] = *(const bf16x8*)(smem + (CB) + boff[nf]); } while (0)
#define RDB23(CB) do { _Pragma("unroll") for (int nf = 0; nf < 2; ++nf)        \
      b23[nf] = *(const bf16x8*)(smem + (CB) + boff[nf + 2]); } while (0)

#define MM(BF, NB) do {                                                        \
    _Pragma("unroll") for (int mf = 0; mf < 4; ++mf)                           \
    _Pragma("unroll") for (int nf = 0; nf < 2; ++nf)                           \
      acc[mf][(NB) + nf] = __builtin_amdgcn_mfma_f32_16x16x32_bf16(            \
          afr[mf], BF[nf], acc[mf][(NB) + nf], 0, 0, 0); } while (0)

  // ---- prologue: tile0 -> buf0, tile1 -> buf1; certify tile0; prefetch reads ----
  STG_ALL(0, 0);
  STG_ALL(1, 24576);
  asm volatile("s_waitcnt vmcnt(3)" ::: "memory");
  __builtin_amdgcn_s_barrier();
  RDA(0); RDB01(0);

  int bc = 0, bs = 2 * 24576;
  for (int t = 0; t < NT; ++t) {
    RDB23(bc);
    STG_ALL(t + 2, bs);
    __builtin_amdgcn_s_setprio(1);
    MM(b01, 0);
    MM(b23, 2);
    __builtin_amdgcn_s_setprio(0);
    asm volatile("s_waitcnt vmcnt(3) lgkmcnt(0)" ::: "memory");
    __builtin_amdgcn_s_barrier();
    const int bn = (bc == 2 * 24576) ? 0 : bc + 24576;
    if (t + 1 < NT) { RDA(bn); RDB01(bn); }
    bc = bn;
    bs = (bs == 2 * 24576) ? 0 : bs + 24576;
  }

  // ---- epilogue: C write (D: col=lane&15, row=(lane>>4)*4+j) ----
  const int r0 = bm0 + wr * 64 + ((lane >> 4) << 2);
  const int c0 = bn0 + wc * 64 + (lane & 15);
  if (OUT_MODE == 3 && bn0 >= 2048) {
    // V columns -> VtOut[b][col-2048][s] (b = row>>11, s = row&2047)
#pragma unroll
    for (int mf = 0; mf < 4; ++mf) {
      const int row0 = r0 + mf * 16;
      const int b = row0 >> 11, s = row0 & 2047;
      unsigned short* Vb = VtOut + (long)b * 2097152;
#pragma unroll
      for (int nf = 0; nf < 4; ++nf) {
        const int col = c0 + nf * 16;
        const float bb = BIAS ? bias[col] : 0.0f;
        f32x4 v = acc[mf][nf];
        ushort4 o;
        o.x = f2bf(v[0] * alpha + bb); o.y = f2bf(v[1] * alpha + bb);
        o.z = f2bf(v[2] * alpha + bb); o.w = f2bf(v[3] * alpha + bb);
        *reinterpret_cast<ushort4*>(Vb + (long)(col - 2048) * 2048 + s) = o;
      }
    }
  } else {
#pragma unroll
    for (int mf = 0; mf < 4; ++mf)
#pragma unroll
      for (int nf = 0; nf < 4; ++nf) {
        const int row0 = r0 + mf * 16;
        const int col = c0 + nf * 16;
        f32x4 v = acc[mf][nf];
        const float bb = BIAS ? bias[col] : 0.0f;
        if (OUT_MODE == 0 || OUT_MODE == 3) {
          unsigned short* C = (unsigned short*)Cv + (long)bz * sC;
#pragma unroll
          for (int j = 0; j < 4; ++j)
            C[(long)(row0 + j) * ldc + col] = f2bf(v[j] * alpha + bb);
        } else {
          float* C = (float*)Cv + (long)bz * sC;
#pragma unroll
          for (int j = 0; j < 4; ++j)
            C[(long)(row0 + j) * ldc + col] = v[j] * alpha + bb;
        }
      }
  }
#undef STG
#undef STG_ALL
#undef RDA
#undef RDB01
#undef RDB23
#undef MM
}

// ---------------- row softmax on bf16 scores, in place ----------------
__global__ __launch_bounds__(256) void k_softmax_bf16(unsigned short* __restrict__ S) {
  long row = blockIdx.x;
  unsigned short* R = S + row * 2048;
  int t = threadIdx.x;
  int wid = t >> 6, lane = t & 63;
  uint4 raw = reinterpret_cast<const uint4*>(R)[t];
  unsigned int w[4] = {raw.x, raw.y, raw.z, raw.w};
  float v[8];
#pragma unroll
  for (int j = 0; j < 4; ++j) {
    v[2 * j]     = __builtin_bit_cast(float, (unsigned int)(w[j] << 16));
    v[2 * j + 1] = __builtin_bit_cast(float, (unsigned int)(w[j] & 0xffff0000u));
  }
  float m = v[0];
#pragma unroll
  for (int j = 1; j < 8; ++j) m = fmaxf(m, v[j]);
#pragma unroll
  for (int off = 32; off >= 1; off >>= 1) m = fmaxf(m, __shfl_xor(m, off));
  __shared__ float red[8];
  if (lane == 0) red[wid] = m;
  __syncthreads();
  m = fmaxf(fmaxf(red[0], red[1]), fmaxf(red[2], red[3]));

  float e[8], s = 0.f;
#pragma unroll
  for (int j = 0; j < 8; ++j) { e[j] = __expf(v[j] - m); s += e[j]; }
#pragma unroll
  for (int off = 32; off >= 1; off >>= 1) s += __shfl_xor(s, off);
  if (lane == 0) red[4 + wid] = s;
  __syncthreads();
  s = red[4] + red[5] + red[6] + red[7];
  float inv = 1.0f / s;

  uint4 o;
  unsigned int* ow = &o.x;
#pragma unroll
  for (int j = 0; j < 4; ++j)
    ow[j] = (unsigned int)f2bf(e[2 * j] * inv) |
            ((unsigned int)f2bf(e[2 * j + 1] * inv) << 16);
  reinterpret_cast<uint4*>(R)[t] = o;
}

extern "C" void kernel_launch(void* const* d_in, const int* in_sizes, int n_in,
                              void* d_out, int out_size, void* d_ws, size_t ws_size,
                              hipStream_t stream) {
  const float* X  = (const float*)d_in[0];
  const float* Wq = (const float*)d_in[1];
  const float* bq = (const float*)d_in[2];
  const float* Wk = (const float*)d_in[3];
  const float* bk = (const float*)d_in[4];
  const float* Wv = (const float*)d_in[5];
  const float* bv = (const float*)d_in[6];
  float* out = (float*)d_out;
  (void)in_sizes; (void)n_in; (void)out_size; (void)ws_size;

  constexpr long S = 2048, H = 1024;
  constexpr long MS = 4 * S;

  size_t off = 0;
  auto alloc = [&](size_t bytes) { char* p = (char*)d_ws + off; off += bytes; return p; };
  unsigned short* Xb    = (unsigned short*)alloc(MS * H * 2);
  unsigned short* Wb    = (unsigned short*)alloc(3 * H * H * 2);
  float*          biasF = (float*)alloc(3 * H * 4);
  unsigned short* QKVb  = (unsigned short*)alloc(MS * 3 * H * 2);
  unsigned short* Vt    = (unsigned short*)alloc(4 * H * S * 2);
  unsigned short* Sb    = (unsigned short*)alloc(4 * S * S * 2);
  (void)Wb;

  // 1) fused converts + bias
  k_prep<<<dim3(11276), 256, 0, stream>>>(X, Wq, Wk, Wv, bq, bk, bv, Xb, biasF);

  // 2) fused QKV = X @ [Wq|Wk|Wv]^T + b; V-cols written transposed to Vt — 768 blocks, 2/CU
  gemm3q<3, 1, 0><<<dim3(12, 64, 1), 512, 0, stream>>>(
      Xb, Xb + MS * H, QKVb, biasF, Vt, 0,
      1024, 1024, 3072, 1024, 1.0f, 0, 0, 0);

  // 3) scores = Q @ K^T / 32 (per batch M=2048, N=2048, K=1024) — 512 blocks, XCD-batch swizzle
  gemm3q<0, 0, 1><<<dim3(512), 512, 0, stream>>>(
      QKVb, QKVb + 1024, Sb, nullptr, nullptr, 8,
      3072, 3072, 2048, 1024, 0.03125f, S * 3 * H, S * 3 * H, S * S);

  // 4) softmax rows in place (bf16)
  k_softmax_bf16<<<dim3((int)MS), 256, 0, stream>>>(Sb);

  // 5) O = P @ V (per batch M=2048, N=1024, K=2048) — 256 blocks, XCD-batch swizzle
  gemm3q<1, 0, 1><<<dim3(256), 512, 0, stream>>>(
      Sb, Vt, out, nullptr, nullptr, 4,
      2048, 2048, 1024, 2048, 1.0f, S * S, H * S, S * H);
}

// Round 18
// 157.797 us; speedup vs baseline: 1.0274x; 1.0274x over previous
//
#include <hip/hip_runtime.h>
#include <stdint.h>

#define ASG __attribute__((address_space(1)))
#define ASL __attribute__((address_space(3)))

typedef __bf16 bf16x8 __attribute__((ext_vector_type(8)));
typedef float f32x4 __attribute__((ext_vector_type(4)));

__device__ __forceinline__ unsigned short f2bf(float f) {
  unsigned int u = __builtin_bit_cast(unsigned int, f);
  u = (u + 0x7fffu + ((u >> 16) & 1u)) >> 16;
  return (unsigned short)u;
}

// ---------------- fused prep: converts X,Wq,Wk,Wv to bf16 + bias concat ----------------
__global__ __launch_bounds__(256) void k_prep(
    const float* __restrict__ X, const float* __restrict__ Wq,
    const float* __restrict__ Wk, const float* __restrict__ Wv,
    const float* __restrict__ bq, const float* __restrict__ bk,
    const float* __restrict__ bv,
    unsigned short* __restrict__ Xb, float* __restrict__ biasF) {
  const int bid = blockIdx.x, tid = threadIdx.x;
  unsigned short* Wb = Xb + 8388608;
  if (bid < 11264) {
    const float* src;
    ushort4* dst;
    int j;
    if (bid < 8192) {
      j = bid * 256 + tid; src = X; dst = (ushort4*)Xb;
    } else {
      int w = (bid - 8192) >> 10;
      j = ((bid - 8192) & 1023) * 256 + tid;
      src = (w == 0) ? Wq : (w == 1 ? Wk : Wv);
      dst = (ushort4*)(Wb + (long)w * 1048576);
    }
    float4 v = reinterpret_cast<const float4*>(src)[j];
    ushort4 o;
    o.x = f2bf(v.x); o.y = f2bf(v.y); o.z = f2bf(v.z); o.w = f2bf(v.w);
    dst[j] = o;
  } else {
    int i = (bid - 11264) * 256 + tid;
    if (i < 3072)
      biasF[i] = (i < 1024) ? bq[i] : (i < 2048 ? bk[i - 1024] : bv[i - 2048]);
  }
}

// =====================================================================
// gemm3q (R16-measured best for QKV+Vt, 65.0us): 128x256 tile, BK=32,
// 8 waves (2Mx4N), 3-buffer LDS ring (72KB -> 2 blocks/CU), ONE barrier
// per K-tile, counted lgkmcnt, next-tile A+B01 prefetch, vmcnt(3)=ring-2.
// OUT_MODE 3: bf16 store; V-cols (bn0>=2048) also -> VtOut[b][h][s].
// =====================================================================
template <int OUT_MODE, int BIAS>
__global__ __launch_bounds__(512, 4) void gemm3q(
    const unsigned short* __restrict__ A, const unsigned short* __restrict__ B,
    void* __restrict__ Cv, const float* __restrict__ bias,
    unsigned short* __restrict__ VtOut,
    int lda, int ldb, int ldc, int K, float alpha) {
  __shared__ __align__(16) char smem[73728];
  const int tid = threadIdx.x;
  const int wid = tid >> 6, lane = tid & 63;
  const int wr = wid >> 2, wc = wid & 3;
  const int bm0 = blockIdx.y << 7, bn0 = blockIdx.x << 8;
  const int NT = K >> 5;

  const int srow = tid >> 2;
  const int scol = (((tid & 3) ^ ((srow >> 1) & 3)) << 3);
  long gA0, gB[2];
  gA0 = (long)(bm0 + srow) * lda + scol;
#pragma unroll
  for (int u = 0; u < 2; ++u)
    gB[u] = (long)(bn0 + u * 128 + srow) * ldb + scol;

#define STG(PTR, GOFF, KK, LDSOFF)                                             \
  __builtin_amdgcn_global_load_lds((ASG const void*)((PTR) + (GOFF) + ((KK) << 5)), \
      (ASL void*)(smem + (LDSOFF) + wid * 1024), 16, 0, 0)
#define STG_ALL(KK, SB_) do { int kk = (KK); if (kk >= NT) kk -= NT;           \
    STG(A, gA0, kk, (SB_));                                                    \
    STG(B, gB[0], kk, (SB_) + 8192);                                           \
    STG(B, gB[1], kk, (SB_) + 16384); } while (0)

  const int L = lane & 15;
  const int blk = ((lane >> 4) ^ ((L >> 1) & 3)) << 4;
  int aoff[4], boff[4];
#pragma unroll
  for (int mf = 0; mf < 4; ++mf)
    aoff[mf] = ((wr * 64 + mf * 16 + L) << 6) + blk;
#pragma unroll
  for (int nf = 0; nf < 4; ++nf)
    boff[nf] = 8192 + ((wc * 64 + nf * 16 + L) << 6) + blk;

  bf16x8 afr[4];
  bf16x8 b01[2], b23[2];
  f32x4 acc[4][4] = {};

#define RDA(CB) do { _Pragma("unroll") for (int mf = 0; mf < 4; ++mf)          \
      afr[mf] = *(const bf16x8*)(smem + (CB) + aoff[mf]); } while (0)
#define RDB01(CB) do { _Pragma("unroll") for (int nf = 0; nf < 2; ++nf)        \
      b01[nf] = *(const bf16x8*)(smem + (CB) + boff[nf]); } while (0)
#define RDB23(CB) do { _Pragma("unroll") for (int nf = 0; nf < 2; ++nf)        \
      b23[nf] = *(const bf16x8*)(smem + (CB) + boff[nf + 2]); } while (0)
#define MM(BF, NB) do {                                                        \
    _Pragma("unroll") for (int mf = 0; mf < 4; ++mf)                           \
    _Pragma("unroll") for (int nf = 0; nf < 2; ++nf)                           \
      acc[mf][(NB) + nf] = __builtin_amdgcn_mfma_f32_16x16x32_bf16(            \
          afr[mf], BF[nf], acc[mf][(NB) + nf], 0, 0, 0); } while (0)

  STG_ALL(0, 0);
  STG_ALL(1, 24576);
  asm volatile("s_waitcnt vmcnt(3)" ::: "memory");
  __builtin_amdgcn_s_barrier();
  RDA(0); RDB01(0);

  int bc = 0, bs = 2 * 24576;
  for (int t = 0; t < NT; ++t) {
    RDB23(bc);
    STG_ALL(t + 2, bs);
    __builtin_amdgcn_s_setprio(1);
    MM(b01, 0);
    MM(b23, 2);
    __builtin_amdgcn_s_setprio(0);
    asm volatile("s_waitcnt vmcnt(3) lgkmcnt(0)" ::: "memory");
    __builtin_amdgcn_s_barrier();
    const int bn = (bc == 2 * 24576) ? 0 : bc + 24576;
    if (t + 1 < NT) { RDA(bn); RDB01(bn); }
    bc = bn;
    bs = (bs == 2 * 24576) ? 0 : bs + 24576;
  }

  const int r0 = bm0 + wr * 64 + ((lane >> 4) << 2);
  const int c0 = bn0 + wc * 64 + (lane & 15);
  if (OUT_MODE == 3 && bn0 >= 2048) {
#pragma unroll
    for (int mf = 0; mf < 4; ++mf) {
      const int row0 = r0 + mf * 16;
      const int b = row0 >> 11, s = row0 & 2047;
      unsigned short* Vb = VtOut + (long)b * 2097152;
#pragma unroll
      for (int nf = 0; nf < 4; ++nf) {
        const int col = c0 + nf * 16;
        const float bb = BIAS ? bias[col] : 0.0f;
        f32x4 v = acc[mf][nf];
        ushort4 o;
        o.x = f2bf(v[0] * alpha + bb); o.y = f2bf(v[1] * alpha + bb);
        o.z = f2bf(v[2] * alpha + bb); o.w = f2bf(v[3] * alpha + bb);
        *reinterpret_cast<ushort4*>(Vb + (long)(col - 2048) * 2048 + s) = o;
      }
    }
  } else {
#pragma unroll
    for (int mf = 0; mf < 4; ++mf)
#pragma unroll
      for (int nf = 0; nf < 4; ++nf) {
        const int row0 = r0 + mf * 16;
        const int col = c0 + nf * 16;
        f32x4 v = acc[mf][nf];
        const float bb = BIAS ? bias[col] : 0.0f;
        unsigned short* C = (unsigned short*)Cv;
#pragma unroll
        for (int j = 0; j < 4; ++j)
          C[(long)(row0 + j) * ldc + col] = f2bf(v[j] * alpha + bb);
      }
  }
#undef STG
#undef STG_ALL
#undef RDA
#undef RDB01
#undef RDB23
#undef MM
}

// =====================================================================
// gemm3p (R15-measured best for SWZ scores/PV, 67.4us combined): 128x256
// tile, BK=64, 8 waves, 3-buffer ring (144KB, 1 block/CU), ONE barrier per
// K-tile, counted lgkmcnt, next-tile prefetch, vmcnt(6)=ring-2.
// SWZ: 1D grid, lid&7 = XCD slot, bz=(lid&7)>>1 (XCD-pair per batch L2).
// OUT_MODE: 0=bf16 store, 1=f32 store.
// =====================================================================
template <int OUT_MODE>
__global__ __launch_bounds__(512, 2) void gemm3p(
    const unsigned short* __restrict__ A, const unsigned short* __restrict__ B,
    void* __restrict__ Cv, int nx,
    int lda, int ldb, int ldc, int K, float alpha,
    long sA, long sB, long sC) {
  __shared__ __align__(16) char smem[147456];
  const int tid = threadIdx.x;
  const int wid = tid >> 6, lane = tid & 63;
  const int wr = wid >> 2, wc = wid & 3;
  const int lid = blockIdx.x;
  const int xcd = lid & 7;
  const int bz = xcd >> 1;
  const int idx = ((lid >> 3) << 1) + (xcd & 1);
  const int bx = idx % nx, by = idx / nx;
  const int bm0 = by << 7, bn0 = bx << 8;
  A += (long)bz * sA;
  B += (long)bz * sB;
  const int NT = K >> 6;

  const int srow = tid >> 3;
  const int scol = (((tid & 7) ^ (srow & 7)) << 3);
  long gA[2], gB[4];
#pragma unroll
  for (int u = 0; u < 2; ++u)
    gA[u] = (long)(bm0 + u * 64 + srow) * lda + scol;
#pragma unroll
  for (int u = 0; u < 4; ++u)
    gB[u] = (long)(bn0 + u * 64 + srow) * ldb + scol;

#define STG(PTR, GOFF, KK, LDSOFF)                                             \
  __builtin_amdgcn_global_load_lds((ASG const void*)((PTR) + (GOFF) + ((KK) << 6)), \
      (ASL void*)(smem + (LDSOFF) + wid * 1024), 16, 0, 0)
#define STG_ALL(KK, SB_) do { int kk = (KK); if (kk >= NT) kk -= NT;           \
    STG(A, gA[0], kk, (SB_));                                                  \
    STG(A, gA[1], kk, (SB_) + 8192);                                           \
    STG(B, gB[0], kk, (SB_) + 16384);                                          \
    STG(B, gB[1], kk, (SB_) + 24576);                                          \
    STG(B, gB[2], kk, (SB_) + 32768);                                          \
    STG(B, gB[3], kk, (SB_) + 40960); } while (0)

  const int arow0 = (wr * 64 + (lane & 15)) << 7;
  const int brow0 = 16384 + ((wc * 64 + (lane & 15)) << 7);
  int colk[2];
#pragma unroll
  for (int ks = 0; ks < 2; ++ks)
    colk[ks] = (((ks << 2) + (lane >> 4)) ^ (lane & 7)) << 4;

  bf16x8 afr2[4][2];
  bf16x8 b01f[2][2], b23f[2][2];
  f32x4 acc[4][4] = {};

#define RDA(CB) do { _Pragma("unroll") for (int mf = 0; mf < 4; ++mf)          \
    _Pragma("unroll") for (int ks = 0; ks < 2; ++ks)                           \
      afr2[mf][ks] = *(const bf16x8*)(smem + (CB) + arow0 + (mf << 11) + colk[ks]); } while (0)
#define RDB01(CB) do { _Pragma("unroll") for (int nf = 0; nf < 2; ++nf)        \
    _Pragma("unroll") for (int ks = 0; ks < 2; ++ks)                           \
      b01f[nf][ks] = *(const bf16x8*)(smem + (CB) + brow0 + (nf << 11) + colk[ks]); } while (0)
#define RDB23(CB) do { _Pragma("unroll") for (int nf = 0; nf < 2; ++nf)        \
    _Pragma("unroll") for (int ks = 0; ks < 2; ++ks)                           \
      b23f[nf][ks] = *(const bf16x8*)(smem + (CB) + brow0 + ((nf + 2) << 11) + colk[ks]); } while (0)
#define MM(BF, NB) do {                                                        \
    _Pragma("unroll") for (int mf = 0; mf < 4; ++mf)                           \
    _Pragma("unroll") for (int nf = 0; nf < 2; ++nf)                           \
    _Pragma("unroll") for (int ks = 0; ks < 2; ++ks)                           \
      acc[mf][(NB) + nf] = __builtin_amdgcn_mfma_f32_16x16x32_bf16(            \
          afr2[mf][ks], BF[nf][ks], acc[mf][(NB) + nf], 0, 0, 0); } while (0)

  STG_ALL(0, 0);
  STG_ALL(1, 49152);
  asm volatile("s_waitcnt vmcnt(6)" ::: "memory");
  __builtin_amdgcn_s_barrier();
  RDA(0); RDB01(0);

  int bc = 0, bs = 2 * 49152;
  for (int t = 0; t < NT; ++t) {
    RDB23(bc);
    STG_ALL(t + 2, bs);
    __builtin_amdgcn_s_setprio(1);
    MM(b01f, 0);
    MM(b23f, 2);
    __builtin_amdgcn_s_setprio(0);
    asm volatile("s_waitcnt vmcnt(6) lgkmcnt(0)" ::: "memory");
    __builtin_amdgcn_s_barrier();
    const int bn = (bc == 2 * 49152) ? 0 : bc + 49152;
    if (t + 1 < NT) { RDA(bn); RDB01(bn); }
    bc = bn;
    bs = (bs == 2 * 49152) ? 0 : bs + 49152;
  }

  const int r0 = bm0 + wr * 64 + ((lane >> 4) << 2);
  const int c0 = bn0 + wc * 64 + (lane & 15);
#pragma unroll
  for (int mf = 0; mf < 4; ++mf)
#pragma unroll
    for (int nf = 0; nf < 4; ++nf) {
      const int row0 = r0 + mf * 16;
      const int col = c0 + nf * 16;
      f32x4 v = acc[mf][nf];
      if (OUT_MODE == 0) {
        unsigned short* C = (unsigned short*)Cv + (long)bz * sC;
#pragma unroll
        for (int j = 0; j < 4; ++j)
          C[(long)(row0 + j) * ldc + col] = f2bf(v[j] * alpha);
      } else {
        float* C = (float*)Cv + (long)bz * sC;
#pragma unroll
        for (int j = 0; j < 4; ++j)
          C[(long)(row0 + j) * ldc + col] = v[j] * alpha;
      }
    }
#undef STG
#undef STG_ALL
#undef RDA
#undef RDB01
#undef RDB23
#undef MM
}

// ---------------- row softmax on bf16 scores, in place ----------------
__global__ __launch_bounds__(256) void k_softmax_bf16(unsigned short* __restrict__ S) {
  long row = blockIdx.x;
  unsigned short* R = S + row * 2048;
  int t = threadIdx.x;
  int wid = t >> 6, lane = t & 63;
  uint4 raw = reinterpret_cast<const uint4*>(R)[t];
  unsigned int w[4] = {raw.x, raw.y, raw.z, raw.w};
  float v[8];
#pragma unroll
  for (int j = 0; j < 4; ++j) {
    v[2 * j]     = __builtin_bit_cast(float, (unsigned int)(w[j] << 16));
    v[2 * j + 1] = __builtin_bit_cast(float, (unsigned int)(w[j] & 0xffff0000u));
  }
  float m = v[0];
#pragma unroll
  for (int j = 1; j < 8; ++j) m = fmaxf(m, v[j]);
#pragma unroll
  for (int off = 32; off >= 1; off >>= 1) m = fmaxf(m, __shfl_xor(m, off));
  __shared__ float red[8];
  if (lane == 0) red[wid] = m;
  __syncthreads();
  m = fmaxf(fmaxf(red[0], red[1]), fmaxf(red[2], red[3]));

  float e[8], s = 0.f;
#pragma unroll
  for (int j = 0; j < 8; ++j) { e[j] = __expf(v[j] - m); s += e[j]; }
#pragma unroll
  for (int off = 32; off >= 1; off >>= 1) s += __shfl_xor(s, off);
  if (lane == 0) red[4 + wid] = s;
  __syncthreads();
  s = red[4] + red[5] + red[6] + red[7];
  float inv = 1.0f / s;

  uint4 o;
  unsigned int* ow = &o.x;
#pragma unroll
  for (int j = 0; j < 4; ++j)
    ow[j] = (unsigned int)f2bf(e[2 * j] * inv) |
            ((unsigned int)f2bf(e[2 * j + 1] * inv) << 16);
  reinterpret_cast<uint4*>(R)[t] = o;
}

extern "C" void kernel_launch(void* const* d_in, const int* in_sizes, int n_in,
                              void* d_out, int out_size, void* d_ws, size_t ws_size,
                              hipStream_t stream) {
  const float* X  = (const float*)d_in[0];
  const float* Wq = (const float*)d_in[1];
  const float* bq = (const float*)d_in[2];
  const float* Wk = (const float*)d_in[3];
  const float* bk = (const float*)d_in[4];
  const float* Wv = (const float*)d_in[5];
  const float* bv = (const float*)d_in[6];
  float* out = (float*)d_out;
  (void)in_sizes; (void)n_in; (void)out_size; (void)ws_size;

  constexpr long S = 2048, H = 1024;
  constexpr long MS = 4 * S;

  size_t off = 0;
  auto alloc = [&](size_t bytes) { char* p = (char*)d_ws + off; off += bytes; return p; };
  unsigned short* Xb    = (unsigned short*)alloc(MS * H * 2);
  unsigned short* Wb    = (unsigned short*)alloc(3 * H * H * 2);
  float*          biasF = (float*)alloc(3 * H * 4);
  unsigned short* QKVb  = (unsigned short*)alloc(MS * 3 * H * 2);
  unsigned short* Vt    = (unsigned short*)alloc(4 * H * S * 2);
  unsigned short* Sb    = (unsigned short*)alloc(4 * S * S * 2);
  (void)Wb;

  // 1) fused converts + bias
  k_prep<<<dim3(11276), 256, 0, stream>>>(X, Wq, Wk, Wv, bq, bk, bv, Xb, biasF);

  // 2) fused QKV = X @ [Wq|Wk|Wv]^T + b; V-cols also -> Vt (gemm3q, R16: 65.0us)
  gemm3q<3, 1><<<dim3(12, 64, 1), 512, 0, stream>>>(
      Xb, Xb + MS * H, QKVb, biasF, Vt, 1024, 1024, 3072, 1024, 1.0f);

  // 3) scores = Q @ K^T / 32 (gemm3p + XCD-batch swizzle, R15)
  gemm3p<0><<<dim3(512), 512, 0, stream>>>(
      QKVb, QKVb + 1024, Sb, 8,
      3072, 3072, 2048, 1024, 0.03125f, S * 3 * H, S * 3 * H, S * S);

  // 4) softmax rows in place (bf16)
  k_softmax_bf16<<<dim3((int)MS), 256, 0, stream>>>(Sb);

  // 5) O = P @ V (gemm3p + XCD-batch swizzle, R15)
  gemm3p<1><<<dim3(256), 512, 0, stream>>>(
      Sb, Vt, out, 4,
      2048, 2048, 1024, 2048, 1.0f, S * S, H * S, S * H);
}